// Round 1
// baseline (2300.363 us; speedup 1.0000x reference)
//
#include <hip/hip_runtime.h>
#include <cmath>

#define NL 16
#define TSIZE (1u << 19)
#define TMASK (TSIZE - 1u)

struct LevelParams {
  float scale[NL];
  unsigned res[NL];
  unsigned dense_mask;
};

__global__ __launch_bounds__(256)
void sdf_fused(const float* __restrict__ dirs,
               const float* __restrict__ table,
               const float* __restrict__ W1, const float* __restrict__ b1,
               const float* __restrict__ W2, const float* __restrict__ b2,
               const float* __restrict__ W3, const float* __restrict__ b3,
               float* __restrict__ out, int n, LevelParams lp)
{
  int gid = blockIdx.x * 256 + threadIdx.x;
  if (gid >= n) return;

  float dx = dirs[gid * 3 + 0];
  float dy = dirs[gid * 3 + 1];
  float dz = dirs[gid * 3 + 2];
  float xx = dx * 0.49f + 0.49f;
  float xy = dy * 0.49f + 0.49f;
  float xz = dz * 0.49f + 0.49f;

  float h[35];
  h[0] = dx; h[1] = dy; h[2] = dz;

  #pragma unroll
  for (int l = 0; l < NL; ++l) {
    float s = lp.scale[l];
    float px = xx * s + 0.5f, py = xy * s + 0.5f, pz = xz * s + 0.5f;
    float gx = floorf(px), gy = floorf(py), gz = floorf(pz);
    float fx = px - gx, fy = py - gy, fz = pz - gz;
    unsigned ix = (unsigned)gx, iy = (unsigned)gy, iz = (unsigned)gz;

    float wx1 = fx * fx * (3.0f - 2.0f * fx);
    float wy1 = fy * fy * (3.0f - 2.0f * fy);
    float wz1 = fz * fz * (3.0f - 2.0f * fz);
    float wx0 = 1.0f - wx1, wy0 = 1.0f - wy1, wz0 = 1.0f - wz1;

    unsigned i000, i100, i010, i110, i001, i101, i011, i111;
    if ((lp.dense_mask >> l) & 1u) {
      unsigned r = lp.res[l];
      unsigned r2 = r * r;
      unsigned x0 = ix, x1 = ix + 1u;
      unsigned y0 = iy * r, y1 = y0 + r;
      unsigned z0 = iz * r2, z1 = z0 + r2;
      i000 = x0 + y0 + z0; i100 = x1 + y0 + z0;
      i010 = x0 + y1 + z0; i110 = x1 + y1 + z0;
      i001 = x0 + y0 + z1; i101 = x1 + y0 + z1;
      i011 = x0 + y1 + z1; i111 = x1 + y1 + z1;
    } else {
      unsigned x0 = ix, x1 = ix + 1u;
      unsigned y0 = iy * 2654435761u, y1 = y0 + 2654435761u;  // uint32 wrap == ref
      unsigned z0 = iz * 805459861u,  z1 = z0 + 805459861u;
      i000 = (x0 ^ y0 ^ z0) & TMASK; i100 = (x1 ^ y0 ^ z0) & TMASK;
      i010 = (x0 ^ y1 ^ z0) & TMASK; i110 = (x1 ^ y1 ^ z0) & TMASK;
      i001 = (x0 ^ y0 ^ z1) & TMASK; i101 = (x1 ^ y0 ^ z1) & TMASK;
      i011 = (x0 ^ y1 ^ z1) & TMASK; i111 = (x1 ^ y1 ^ z1) & TMASK;
    }

    const float2* t = (const float2*)table + (size_t)l * TSIZE;
    float2 f000 = t[i000], f100 = t[i100], f010 = t[i010], f110 = t[i110];
    float2 f001 = t[i001], f101 = t[i101], f011 = t[i011], f111 = t[i111];

    float wy0z0 = wy0 * wz0, wy1z0 = wy1 * wz0, wy0z1 = wy0 * wz1, wy1z1 = wy1 * wz1;
    float w000 = wx0 * wy0z0, w100 = wx1 * wy0z0;
    float w010 = wx0 * wy1z0, w110 = wx1 * wy1z0;
    float w001 = wx0 * wy0z1, w101 = wx1 * wy0z1;
    float w011 = wx0 * wy1z1, w111 = wx1 * wy1z1;

    float a0 = w000 * f000.x + w100 * f100.x + w010 * f010.x + w110 * f110.x
             + w001 * f001.x + w101 * f101.x + w011 * f011.x + w111 * f111.x;
    float a1 = w000 * f000.y + w100 * f100.y + w010 * f010.y + w110 * f110.y
             + w001 * f001.y + w101 * f101.y + w011 * f011.y + w111 * f111.y;
    h[3 + 2 * l] = a0;
    h[4 + 2 * l] = a1;
  }

  // ---- MLP: weights are wave-uniform, compile-time offsets -> scalar loads ----
  float h1[64];
  #pragma unroll
  for (int j = 0; j < 64; ++j) {
    float acc = b1[j];
    #pragma unroll
    for (int i = 0; i < 35; ++i) acc = fmaf(h[i], W1[i * 64 + j], acc);
    h1[j] = fmaxf(acc, 0.0f);
  }

  float h2[64];
  #pragma unroll
  for (int j = 0; j < 64; ++j) {
    float acc = b2[j];
    #pragma unroll
    for (int i = 0; i < 64; ++i) acc = fmaf(h1[i], W2[i * 64 + j], acc);
    h2[j] = fmaxf(acc, 0.0f);
  }

  float o = b3[0];
  #pragma unroll
  for (int i = 0; i < 64; ++i) o = fmaf(h2[i], W3[i], o);

  float v = o + 1.0f;
  // softplus = logaddexp(v, 0) = max(v,0) + log1p(exp(-|v|))
  out[gid] = fmaxf(v, 0.0f) + log1pf(expf(-fabsf(v)));
}

extern "C" void kernel_launch(void* const* d_in, const int* in_sizes, int n_in,
                              void* d_out, int out_size, void* d_ws, size_t ws_size,
                              hipStream_t stream) {
  const float* dirs  = (const float*)d_in[0];
  const float* table = (const float*)d_in[1];
  const float* W1 = (const float*)d_in[2];
  const float* b1 = (const float*)d_in[3];
  const float* W2 = (const float*)d_in[4];
  const float* b2 = (const float*)d_in[5];
  const float* W3 = (const float*)d_in[6];
  const float* b3 = (const float*)d_in[7];
  float* out = (float*)d_out;
  int n = in_sizes[0] / 3;

  LevelParams lp;
  double pls = std::exp(std::log(2048.0 / 16.0) / 15.0);
  unsigned dm = 0;
  for (int l = 0; l < NL; ++l) {
    double scale = 16.0 * std::pow(pls, (double)l) - 1.0;
    lp.scale[l] = (float)scale;
    long long res = (long long)std::ceil(scale) + 1;
    lp.res[l] = (unsigned)res;
    if (res * res * res <= (long long)TSIZE) dm |= (1u << l);
  }
  lp.dense_mask = dm;

  int blocks = (n + 255) / 256;
  hipLaunchKernelGGL(sdf_fused, dim3(blocks), dim3(256), 0, stream,
                     dirs, table, W1, b1, W2, b2, W3, b3, out, n, lp);
}